// Round 1
// baseline (285.442 us; speedup 1.0000x reference)
//
#include <hip/hip_runtime.h>
#include <hip/hip_bf16.h>
#include <stdint.h>

// Problem constants
#define BB 4
#define SXN 4096
#define SYN 4096
#define DD 1024
#define HH 64

typedef float f32x4 __attribute__((ext_vector_type(4)));
typedef short bf16x8 __attribute__((ext_vector_type(8)));

static __device__ __forceinline__ unsigned short f2bf(float f) {
  // round-to-nearest-even f32 -> bf16 (inputs are finite; no NaN handling needed)
  unsigned int u = __float_as_uint(f);
  u += 0x7fffu + ((u >> 16) & 1u);
  return (unsigned short)(u >> 16);
}
static __device__ __forceinline__ float bf2f(unsigned short b) {
  return __uint_as_float(((unsigned int)b) << 16);
}

// ---------------------------------------------------------------------------
// Kernel 0: W [1024][64] f32 -> Wt [3][64][1024] bf16 (mats: 0=Wk, 1=Wv, 2=Wq)
// Transposed so proj B-fragments (lane reads Wt[h][k..k+7]) are contiguous 16B.
// ---------------------------------------------------------------------------
__global__ __launch_bounds__(256) void prep_wt(
    const float* __restrict__ Wq, const float* __restrict__ Wk,
    const float* __restrict__ Wv, unsigned short* __restrict__ Wt) {
  int gid = blockIdx.x * 256 + threadIdx.x;  // grid 768 -> exactly 3*64*1024
  int mat = gid >> 16;
  int h = (gid >> 10) & 63;
  int k = gid & 1023;
  const float* W = (mat == 0) ? Wk : (mat == 1) ? Wv : Wq;
  Wt[gid] = f2bf(W[k * HH + h]);
}

// ---------------------------------------------------------------------------
// Kernel 1: projections.
//  blockIdx.y==0: from x -> Kb [b][sx][64] (row-major) and Vt [b][64][sx] (transposed)
//  blockIdx.y==1: from y -> Qb [b][sy][64], scaled by H^-0.5 = 0.125
// 64 rows x 64 cols per block, K-loop 1024 in steps of 64. 4 waves, 16 rows each.
// LDS x-tile [64][72] bf16: pitch 144 B = 9*16 (keeps 16B alignment), conflicts ~2-way.
// ---------------------------------------------------------------------------
__global__ __launch_bounds__(256) void proj_kernel(
    const float* __restrict__ xin, const float* __restrict__ yin,
    const unsigned short* __restrict__ Wt,
    unsigned short* __restrict__ Qb, unsigned short* __restrict__ Kb,
    unsigned short* __restrict__ Vt) {
  __shared__ __align__(16) unsigned short xa[64][72];
  const int tid = threadIdx.x;
  const int w = tid >> 6;
  const int l = tid & 63;
  const int li = l & 15, lg = l >> 4;
  const int row0 = blockIdx.x * 64;  // flat row in [0, 16384)
  const bool qpath = (blockIdx.y == 1);
  const float* src = qpath ? yin : xin;

  const unsigned short* WtA = qpath ? (Wt + 2 * 65536) : Wt;  // Wq or Wk
  const unsigned short* WtB = Wt + 65536;                     // Wv

  f32x4 acc0[4], acc1[4];
  const f32x4 z4 = {0.f, 0.f, 0.f, 0.f};
#pragma unroll
  for (int i = 0; i < 4; ++i) { acc0[i] = z4; acc1[i] = z4; }

  for (int ks = 0; ks < 16; ++ks) {
    // stage 64x64 f32 -> bf16 LDS (coalesced: 16 threads * float4 per row)
#pragma unroll
    for (int p = 0; p < 4; ++p) {
      int r = p * 16 + (tid >> 4);
      int c = (tid & 15) * 4;
      const float4 v = *reinterpret_cast<const float4*>(
          &src[(size_t)(row0 + r) * DD + ks * 64 + c]);
      ushort4 o;
      o.x = f2bf(v.x); o.y = f2bf(v.y); o.z = f2bf(v.z); o.w = f2bf(v.w);
      *reinterpret_cast<ushort4*>(&xa[r][c]) = o;
    }
    __syncthreads();

    const bf16x8 a0 = *reinterpret_cast<const bf16x8*>(&xa[w * 16 + li][lg * 8]);
    const bf16x8 a1 = *reinterpret_cast<const bf16x8*>(&xa[w * 16 + li][32 + lg * 8]);

#pragma unroll
    for (int hb = 0; hb < 4; ++hb) {
      const int wrow = hb * 16 + li;
      const bf16x8 b0 = *reinterpret_cast<const bf16x8*>(
          &WtA[wrow * 1024 + ks * 64 + lg * 8]);
      const bf16x8 b1 = *reinterpret_cast<const bf16x8*>(
          &WtA[wrow * 1024 + ks * 64 + 32 + lg * 8]);
      acc0[hb] = __builtin_amdgcn_mfma_f32_16x16x32_bf16(a0, b0, acc0[hb], 0, 0, 0);
      acc0[hb] = __builtin_amdgcn_mfma_f32_16x16x32_bf16(a1, b1, acc0[hb], 0, 0, 0);
    }
    if (!qpath) {
#pragma unroll
      for (int hb = 0; hb < 4; ++hb) {
        const int wrow = hb * 16 + li;
        const bf16x8 b0 = *reinterpret_cast<const bf16x8*>(
            &WtB[wrow * 1024 + ks * 64 + lg * 8]);
        const bf16x8 b1 = *reinterpret_cast<const bf16x8*>(
            &WtB[wrow * 1024 + ks * 64 + 32 + lg * 8]);
        acc1[hb] = __builtin_amdgcn_mfma_f32_16x16x32_bf16(a0, b0, acc1[hb], 0, 0, 0);
        acc1[hb] = __builtin_amdgcn_mfma_f32_16x16x32_bf16(a1, b1, acc1[hb], 0, 0, 0);
      }
    }
    __syncthreads();
  }

  // epilogue: C/D layout row=(l>>4)*4+r, col=l&15 (m89-verified)
  const int rbase = row0 + w * 16 + lg * 4;
  if (qpath) {
#pragma unroll
    for (int hb = 0; hb < 4; ++hb)
#pragma unroll
      for (int r = 0; r < 4; ++r)
        Qb[(size_t)(rbase + r) * HH + hb * 16 + li] = f2bf(acc0[hb][r] * 0.125f);
  } else {
#pragma unroll
    for (int hb = 0; hb < 4; ++hb)
#pragma unroll
      for (int r = 0; r < 4; ++r)
        Kb[(size_t)(rbase + r) * HH + hb * 16 + li] = f2bf(acc0[hb][r]);
    const int b = rbase >> 12;     // row / 4096 (64 | 4096, no straddle)
    const int sx = rbase & 4095;
#pragma unroll
    for (int hb = 0; hb < 4; ++hb) {
      ushort4 o;
      o.x = f2bf(acc1[hb][0]); o.y = f2bf(acc1[hb][1]);
      o.z = f2bf(acc1[hb][2]); o.w = f2bf(acc1[hb][3]);
      *reinterpret_cast<ushort4*>(
          &Vt[((size_t)b * HH + hb * 16 + li) * SXN + sx]) = o;
    }
  }
}

// ---------------------------------------------------------------------------
// Kernel 2: flash attention. grid (Sy/64, B), 256 threads = 4 waves x 16 q-rows.
// Per 64-key step: stage K [64][64] and V^T [64][64] bf16 in LDS (pitch 72),
// QK^T -> mask -> online softmax (exp2) -> P via LDS relayout -> PV.
// ---------------------------------------------------------------------------
__global__ __launch_bounds__(256) void flash_kernel(
    const unsigned short* __restrict__ Qb, const unsigned short* __restrict__ Kb,
    const unsigned short* __restrict__ Vt, const int* __restrict__ vlx_p,
    const int* __restrict__ vly_p, const int* __restrict__ uc_p,
    float* __restrict__ out) {
  __shared__ __align__(16) unsigned short Kt[64][72];
  __shared__ __align__(16) unsigned short Vl[64][72];
  __shared__ __align__(16) unsigned short Pl[4][16][72];

  const int tid = threadIdx.x;
  const int w = tid >> 6, l = tid & 63;
  const int li = l & 15, lg = l >> 4;
  const int qt = blockIdx.x, b = blockIdx.y;
  const int q0 = qt * 64;
  const int vlx = vlx_p[b], vly = vly_p[b];
  const int causal = uc_p[0];
  const float LOG2E = 1.4426950408889634f;

  float* outB = out + (size_t)b * SYN * HH;

  if (q0 >= vly) {  // whole q-tile masked -> zeros (uniform branch, pre-barrier)
    const float4 z = make_float4(0.f, 0.f, 0.f, 0.f);
#pragma unroll
    for (int i = 0; i < 4; ++i)
      *reinterpret_cast<float4*>(&outB[(size_t)q0 * HH + tid * 16 + i * 4]) = z;
    return;
  }

  int kend = causal ? min(vlx, q0 + 64) : vlx;
  if (kend > SXN) kend = SXN;
  const int nsteps = (kend + 63) >> 6;  // >= 1 (vlx >= 1)

  // Q fragments, hoisted (scale already folded in at projection)
  const unsigned short* Qrow = Qb + ((size_t)b * SYN + q0 + w * 16 + li) * HH;
  const bf16x8 qa0 = *reinterpret_cast<const bf16x8*>(&Qrow[lg * 8]);
  const bf16x8 qa1 = *reinterpret_cast<const bf16x8*>(&Qrow[32 + lg * 8]);

  const unsigned short* KbB = Kb + (size_t)b * SXN * HH;
  const unsigned short* VtB = Vt + (size_t)b * HH * SXN;

  f32x4 o[4];
  float mrun[4], lrun[4];
  const f32x4 z4 = {0.f, 0.f, 0.f, 0.f};
#pragma unroll
  for (int i = 0; i < 4; ++i) { o[i] = z4; mrun[i] = -INFINITY; lrun[i] = 0.f; }

  const int qg0 = q0 + w * 16 + lg * 4;

  for (int s = 0; s < nsteps; ++s) {
    const int key0 = s << 6;
    {  // stage K and V^T tiles: 8 threads x 16B per 128B row, 32 rows/pass
      const int r = tid >> 3, c = (tid & 7) * 8;
      *reinterpret_cast<uint4*>(&Kt[r][c]) =
          *reinterpret_cast<const uint4*>(&KbB[(size_t)(key0 + r) * HH + c]);
      *reinterpret_cast<uint4*>(&Kt[r + 32][c]) =
          *reinterpret_cast<const uint4*>(&KbB[(size_t)(key0 + r + 32) * HH + c]);
      *reinterpret_cast<uint4*>(&Vl[r][c]) =
          *reinterpret_cast<const uint4*>(&VtB[(size_t)r * SXN + key0 + c]);
      *reinterpret_cast<uint4*>(&Vl[r + 32][c]) =
          *reinterpret_cast<const uint4*>(&VtB[(size_t)(r + 32) * SXN + key0 + c]);
    }
    __syncthreads();

    // QK^T: S[q][key], 4 key-fragments of 16
    f32x4 sa[4];
#pragma unroll
    for (int kb = 0; kb < 4; ++kb) {
      const bf16x8 k0 = *reinterpret_cast<const bf16x8*>(&Kt[kb * 16 + li][lg * 8]);
      const bf16x8 k1 = *reinterpret_cast<const bf16x8*>(&Kt[kb * 16 + li][32 + lg * 8]);
      f32x4 acc = z4;
      acc = __builtin_amdgcn_mfma_f32_16x16x32_bf16(qa0, k0, acc, 0, 0, 0);
      acc = __builtin_amdgcn_mfma_f32_16x16x32_bf16(qa1, k1, acc, 0, 0, 0);
      sa[kb] = acc;
    }

    // mask + online softmax, per accumulator row r (q = qg0 + r)
#pragma unroll
    for (int r = 0; r < 4; ++r) {
      const int qcap = causal ? (qg0 + r) : 0x7fffffff;
      float sv[4];
#pragma unroll
      for (int kb = 0; kb < 4; ++kb) {
        const int kg = key0 + kb * 16 + li;
        const bool valid = (kg < vlx) && (kg <= qcap);
        sv[kb] = valid ? sa[kb][r] : -1e30f;
      }
      float tm = fmaxf(fmaxf(sv[0], sv[1]), fmaxf(sv[2], sv[3]));
      tm = fmaxf(tm, __shfl_xor(tm, 1));
      tm = fmaxf(tm, __shfl_xor(tm, 2));
      tm = fmaxf(tm, __shfl_xor(tm, 4));
      tm = fmaxf(tm, __shfl_xor(tm, 8));
      const float mn = fmaxf(mrun[r], tm);
      const float corr = exp2f((mrun[r] - mn) * LOG2E);  // -inf first step -> 0
      mrun[r] = mn;
      float ps = 0.f;
#pragma unroll
      for (int kb = 0; kb < 4; ++kb) {
        const float p = exp2f((sv[kb] - mn) * LOG2E);
        const unsigned short pb = f2bf(p);
        Pl[w][lg * 4 + r][kb * 16 + li] = pb;
        ps += bf2f(pb);  // sum the *rounded* weights -> consistent normalization
      }
      ps += __shfl_xor(ps, 1);
      ps += __shfl_xor(ps, 2);
      ps += __shfl_xor(ps, 4);
      ps += __shfl_xor(ps, 8);
      lrun[r] = lrun[r] * corr + ps;
#pragma unroll
      for (int df = 0; df < 4; ++df) o[df][r] *= corr;
    }

    // PV: A = P (relayout via per-wave LDS buffer), B = V^T tile
#pragma unroll
    for (int kh = 0; kh < 2; ++kh) {
      const bf16x8 pa = *reinterpret_cast<const bf16x8*>(&Pl[w][li][kh * 32 + lg * 8]);
#pragma unroll
      for (int df = 0; df < 4; ++df) {
        const bf16x8 vb =
            *reinterpret_cast<const bf16x8*>(&Vl[df * 16 + li][kh * 32 + lg * 8]);
        o[df] = __builtin_amdgcn_mfma_f32_16x16x32_bf16(pa, vb, o[df], 0, 0, 0);
      }
    }
    __syncthreads();  // protect Kt/Vl before next stage
  }

  // epilogue: normalize, zero invalid q rows
#pragma unroll
  for (int r = 0; r < 4; ++r) {
    const int qg = qg0 + r;
    const float inv = (lrun[r] > 0.f) ? 1.0f / lrun[r] : 0.f;
    const bool rowvalid = (qg < vly);
    float* orow = &outB[(size_t)qg * HH];
#pragma unroll
    for (int df = 0; df < 4; ++df) {
      const float val = rowvalid ? o[df][r] * inv : 0.f;
      orow[df * 16 + li] = val;
    }
  }
}

// ---------------------------------------------------------------------------
extern "C" void kernel_launch(void* const* d_in, const int* in_sizes, int n_in,
                              void* d_out, int out_size, void* d_ws, size_t ws_size,
                              hipStream_t stream) {
  const float* x = (const float*)d_in[0];
  const float* y = (const float*)d_in[1];
  const int* vlx = (const int*)d_in[2];
  const int* vly = (const int*)d_in[3];
  const int* uc = (const int*)d_in[4];
  const float* Wq = (const float*)d_in[5];
  const float* Wk = (const float*)d_in[6];
  const float* Wv = (const float*)d_in[7];
  float* out = (float*)d_out;

  char* ws = (char*)d_ws;
  unsigned short* Qb = (unsigned short*)(ws);                  // 2 MB
  unsigned short* Kb = (unsigned short*)(ws + (2u << 20));     // 2 MB
  unsigned short* Vt = (unsigned short*)(ws + (4u << 20));     // 2 MB
  unsigned short* Wt = (unsigned short*)(ws + (6u << 20));     // 384 KB

  prep_wt<<<768, 256, 0, stream>>>(Wq, Wk, Wv, Wt);
  proj_kernel<<<dim3(256, 2), 256, 0, stream>>>(x, y, Wt, Qb, Kb, Vt);
  flash_kernel<<<dim3(64, 4), 256, 0, stream>>>(Qb, Kb, Vt, vlx, vly, uc, out);
}

// Round 5
// 268.016 us; speedup vs baseline: 1.0650x; 1.0650x over previous
//
#include <hip/hip_runtime.h>
#include <hip/hip_bf16.h>
#include <stdint.h>

// Problem constants
#define BBATCH 4
#define SXN 4096
#define SYN 4096
#define DD 1024
#define HH 64

typedef float f32x4 __attribute__((ext_vector_type(4)));
typedef short bf16x8 __attribute__((ext_vector_type(8)));

static __device__ __forceinline__ unsigned short f2bf(float f) {
  // round-to-nearest-even f32 -> bf16 (inputs finite)
  unsigned int u = __float_as_uint(f);
  u += 0x7fffu + ((u >> 16) & 1u);
  return (unsigned short)(u >> 16);
}
static __device__ __forceinline__ float bf2f(unsigned short b) {
  return __uint_as_float(((unsigned int)b) << 16);
}

static __device__ __forceinline__ bf16x8 cvt8(f32x4 lo, f32x4 hi) {
  bf16x8 v;
  v[0] = (short)f2bf(lo[0]); v[1] = (short)f2bf(lo[1]);
  v[2] = (short)f2bf(lo[2]); v[3] = (short)f2bf(lo[3]);
  v[4] = (short)f2bf(hi[0]); v[5] = (short)f2bf(hi[1]);
  v[6] = (short)f2bf(hi[2]); v[7] = (short)f2bf(hi[3]);
  return v;
}

// async global->LDS DMA, 16B per lane; LDS dest = wave-uniform base + lane*16
static __device__ __forceinline__ void gload_lds16(const void* g, void* l) {
  __builtin_amdgcn_global_load_lds(
      (const __attribute__((address_space(1))) unsigned int*)g,
      (__attribute__((address_space(3))) unsigned int*)l, 16, 0, 0);
}

// ---------------------------------------------------------------------------
// Kernel 0: W [1024][64] f32 -> Wt [3][64][1024] bf16 (0=Wk, 1=Wv, 2=Wq)
// ---------------------------------------------------------------------------
__global__ __launch_bounds__(256) void prep_wt(
    const float* __restrict__ Wq, const float* __restrict__ Wk,
    const float* __restrict__ Wv, unsigned short* __restrict__ Wt) {
  int gid = blockIdx.x * 256 + threadIdx.x;  // grid 768 = 3*64*1024/256
  int mat = gid >> 16;
  int k = gid & 1023;
  int h = (gid >> 10) & 63;
  const float* W = (mat == 0) ? Wk : (mat == 1) ? Wv : Wq;
  Wt[gid] = f2bf(W[k * HH + h]);
}

// ---------------------------------------------------------------------------
// Kernel 1: projections (streaming, global_load_lds double-buffered).
//  blocks 0..255   : x rows -> Kb [b][sx][64] and Vt [b][64][sx]
//  blocks 256..511 : y rows -> Qb [b][sy][64] (scale 0.125 folded in)
// LDS x-tile [64][64] f32 linear (required by DMA); source cols pre-swizzled
// with col16 ^= (row&7) so swizzled reads are ~conflict-free (rule #21).
// ---------------------------------------------------------------------------
__global__ __launch_bounds__(256, 3) void proj_kernel(
    const float* __restrict__ xin, const float* __restrict__ yin,
    const unsigned short* __restrict__ Wt,
    unsigned short* __restrict__ Qb, unsigned short* __restrict__ Kb,
    unsigned short* __restrict__ Vt) {
  __shared__ __align__(16) float xa[2][64 * 64];  // 2 x 16 KB
  const int tid = threadIdx.x;
  const int w = tid >> 6, l = tid & 63;
  const int li = l & 15, lg = l >> 4;
  const bool qpath = blockIdx.x >= 256;
  const int row0 = (qpath ? (blockIdx.x - 256) : (int)blockIdx.x) * 64;
  const float* src = qpath ? yin : xin;
  const unsigned short* WtA = qpath ? (Wt + 2 * 65536) : Wt;  // Wq or Wk
  const unsigned short* WtB = Wt + 65536;                     // Wv

  f32x4 acc0[4], acc1[4];
  const f32x4 z4 = {0.f, 0.f, 0.f, 0.f};
#pragma unroll
  for (int i = 0; i < 4; ++i) { acc0[i] = z4; acc1[i] = z4; }

  // stage chunk kc (64 f32 cols) into buffer b: per wave 4 DMA issues of 1KB
  auto stage = [&](int bsel, int kc) {
#pragma unroll
    for (int i = 0; i < 4; ++i) {
      const int r = i * 16 + w * 4 + (l >> 4);      // tile row this lane feeds
      const int c16 = (l & 15) ^ (r & 7);           // pre-swizzled 16B chunk
      const float* g = src + (size_t)(row0 + r) * DD + kc * 64 + c16 * 4;
      float* lp = &xa[bsel][i * 1024 + w * 256];    // wave-uniform LDS base
      gload_lds16(g, lp);
    }
  };

  int buf = 0;
  stage(0, 0);
  __syncthreads();
  for (int kc = 0; kc < 16; ++kc) {
    if (kc < 15) stage(buf ^ 1, kc + 1);
    const int rrow = w * 16 + li;
    const int swz = (rrow & 7) * 4;  // element-granule XOR (== 16B-chunk XOR)
#pragma unroll
    for (int ks = 0; ks < 2; ++ks) {
      const int base = rrow * 64 + ks * 32 + lg * 8;
      const f32x4 lo = *reinterpret_cast<const f32x4*>(&xa[buf][base ^ swz]);
      const f32x4 hi = *reinterpret_cast<const f32x4*>(&xa[buf][(base + 4) ^ swz]);
      const bf16x8 a = cvt8(lo, hi);
      const int gks = kc * 2 + ks;
#pragma unroll
      for (int hb = 0; hb < 4; ++hb) {
        const bf16x8 b0 = *reinterpret_cast<const bf16x8*>(
            &WtA[(hb * 16 + li) * 1024 + gks * 32 + lg * 8]);
        acc0[hb] = __builtin_amdgcn_mfma_f32_16x16x32_bf16(a, b0, acc0[hb], 0, 0, 0);
      }
      if (!qpath) {
#pragma unroll
        for (int hb = 0; hb < 4; ++hb) {
          const bf16x8 b1 = *reinterpret_cast<const bf16x8*>(
              &WtB[(hb * 16 + li) * 1024 + gks * 32 + lg * 8]);
          acc1[hb] = __builtin_amdgcn_mfma_f32_16x16x32_bf16(a, b1, acc1[hb], 0, 0, 0);
        }
      }
    }
    __syncthreads();
    buf ^= 1;
  }

  // epilogue: C/D layout row=(l>>4)*4+r, col=l&15 (m89-verified)
  const int rbase = row0 + w * 16 + lg * 4;
  if (qpath) {
#pragma unroll
    for (int hb = 0; hb < 4; ++hb)
#pragma unroll
      for (int r = 0; r < 4; ++r)
        Qb[(size_t)(rbase + r) * HH + hb * 16 + li] = f2bf(acc0[hb][r] * 0.125f);
  } else {
#pragma unroll
    for (int hb = 0; hb < 4; ++hb)
#pragma unroll
      for (int r = 0; r < 4; ++r)
        Kb[(size_t)(rbase + r) * HH + hb * 16 + li] = f2bf(acc0[hb][r]);
    const int b = rbase >> 12;   // row / 4096 (tiles never straddle batches)
    const int sx = rbase & 4095;
#pragma unroll
    for (int hb = 0; hb < 4; ++hb) {
      ushort4 o;
      o.x = f2bf(acc1[hb][0]); o.y = f2bf(acc1[hb][1]);
      o.z = f2bf(acc1[hb][2]); o.w = f2bf(acc1[hb][3]);
      *reinterpret_cast<ushort4*>(
          &Vt[((size_t)b * HH + hb * 16 + li) * SXN + sx]) = o;
    }
  }
}

// ---------------------------------------------------------------------------
// Kernel 2: flash attention, in-block key-split.
// grid 512 x 512thr. Block = (batch b, row-block rb of 32 q-rows).
// 8 waves = 2 row-groups(16 rows) x 4 key-chunks of the causal key range.
// K/V fragments read directly from global (L2-resident, ~1MB/batch).
// Per-wave online softmax partials (m,l,o) merged across chunks via LDS.
// Block swizzle: batch b pinned to XCDs {2b,2b+1}; longest rb dispatched first.
// ---------------------------------------------------------------------------
__global__ __launch_bounds__(512, 4) void flash_kernel(
    const unsigned short* __restrict__ Qb, const unsigned short* __restrict__ Kb,
    const unsigned short* __restrict__ Vt, const int* __restrict__ vlx_p,
    const int* __restrict__ vly_p, const int* __restrict__ uc_p,
    float* __restrict__ out) {
  __shared__ __align__(16) unsigned short Pl[8][16][72];  // 18 KB
  __shared__ __align__(16) float Ol[8][16][64];           // 32 KB
  __shared__ float Ml[8][16], Ll[8][16];                  // 1 KB

  const int tid = threadIdx.x;
  const int w = tid >> 6, l = tid & 63;
  const int li = l & 15, lg = l >> 4;
  const int rg = w & 1, c = w >> 1;

  const int kblk = blockIdx.x;
  const int b = (kblk & 7) >> 1;                           // XCD-affine batch
  const int rb = 127 - (((kblk >> 3) << 1) | (kblk & 1));  // longest first
  const int q0 = rb * 32;
  const int vlx = vlx_p[b], vly = vly_p[b];
  const int causal = uc_p[0];
  const float LOG2E = 1.4426950408889634f;

  const int qbase = q0 + rg * 16;
  int kend = causal ? min(vlx, qbase + 16) : vlx;
  if (kend > SXN) kend = SXN;
  const int nst = (kend + 63) >> 6;
  const int s0 = (c * nst) >> 2;
  const int s1 = ((c + 1) * nst) >> 2;

  const unsigned short* KbB = Kb + (size_t)b * SXN * HH;
  const unsigned short* VtB = Vt + (size_t)b * HH * SXN;

  f32x4 o[4];
  float mrun[4], lrun[4];
  const f32x4 z4 = {0.f, 0.f, 0.f, 0.f};
#pragma unroll
  for (int i = 0; i < 4; ++i) { o[i] = z4; mrun[i] = -INFINITY; lrun[i] = 0.f; }

  const bool active = (qbase < vly);
  const int qg0 = qbase + lg * 4;

  if (active && s1 > s0) {
    const unsigned short* Qrow = Qb + ((size_t)b * SYN + qbase + li) * HH;
    const bf16x8 qa0 = *reinterpret_cast<const bf16x8*>(&Qrow[lg * 8]);
    const bf16x8 qa1 = *reinterpret_cast<const bf16x8*>(&Qrow[32 + lg * 8]);

    for (int s = s0; s < s1; ++s) {
      const int key0 = s << 6;
      // QK^T: 8 K-fragments straight from L2
      f32x4 sa[4];
#pragma unroll
      for (int kb = 0; kb < 4; ++kb) {
        const unsigned short* Kr = &KbB[(size_t)(key0 + kb * 16 + li) * HH];
        const bf16x8 k0 = *reinterpret_cast<const bf16x8*>(&Kr[lg * 8]);
        const bf16x8 k1 = *reinterpret_cast<const bf16x8*>(&Kr[32 + lg * 8]);
        f32x4 acc = z4;
        acc = __builtin_amdgcn_mfma_f32_16x16x32_bf16(qa0, k0, acc, 0, 0, 0);
        acc = __builtin_amdgcn_mfma_f32_16x16x32_bf16(qa1, k1, acc, 0, 0, 0);
        sa[kb] = acc;
      }

      // mask + online softmax per accumulator row r (q = qg0 + r)
#pragma unroll
      for (int r = 0; r < 4; ++r) {
        const int qcap = causal ? (qg0 + r) : 0x7fffffff;
        float sv[4];
#pragma unroll
        for (int kb = 0; kb < 4; ++kb) {
          const int kg = key0 + kb * 16 + li;
          const bool valid = (kg < vlx) && (kg <= qcap);
          sv[kb] = valid ? sa[kb][r] : -1e30f;
        }
        float tm = fmaxf(fmaxf(sv[0], sv[1]), fmaxf(sv[2], sv[3]));
        tm = fmaxf(tm, __shfl_xor(tm, 1));
        tm = fmaxf(tm, __shfl_xor(tm, 2));
        tm = fmaxf(tm, __shfl_xor(tm, 4));
        tm = fmaxf(tm, __shfl_xor(tm, 8));
        const float mn = fmaxf(mrun[r], tm);
        const float corr = exp2f((mrun[r] - mn) * LOG2E);
        mrun[r] = mn;
        float ps = 0.f;
#pragma unroll
        for (int kb = 0; kb < 4; ++kb) {
          const float p = exp2f((sv[kb] - mn) * LOG2E);
          const unsigned short pb = f2bf(p);
          Pl[w][lg * 4 + r][kb * 16 + li] = pb;
          ps += bf2f(pb);  // sum rounded weights -> consistent normalization
        }
        ps += __shfl_xor(ps, 1);
        ps += __shfl_xor(ps, 2);
        ps += __shfl_xor(ps, 4);
        ps += __shfl_xor(ps, 8);
        lrun[r] = lrun[r] * corr + ps;
#pragma unroll
        for (int df = 0; df < 4; ++df) o[df][r] *= corr;
      }

      // PV: A = P (per-wave LDS relayout), B = V^T fragments from L2
#pragma unroll
      for (int kh = 0; kh < 2; ++kh) {
        const bf16x8 pa =
            *reinterpret_cast<const bf16x8*>(&Pl[w][li][kh * 32 + lg * 8]);
#pragma unroll
        for (int df = 0; df < 4; ++df) {
          const bf16x8 vb = *reinterpret_cast<const bf16x8*>(
              &VtB[(size_t)(df * 16 + li) * SXN + key0 + kh * 32 + lg * 8]);
          o[df] = __builtin_amdgcn_mfma_f32_16x16x32_bf16(pa, vb, o[df], 0, 0, 0);
        }
      }
    }
  }

  // publish partials (C layout: lane holds rows lg*4+r, cols df*16+li)
  if (active) {
#pragma unroll
    for (int df = 0; df < 4; ++df)
#pragma unroll
      for (int r = 0; r < 4; ++r)
        Ol[w][lg * 4 + r][df * 16 + li] = o[df][r];
    if (li == 0) {
#pragma unroll
      for (int r = 0; r < 4; ++r) {
        Ml[w][lg * 4 + r] = mrun[r];
        Ll[w][lg * 4 + r] = lrun[r];
      }
    }
  }
  __syncthreads();

  // merge the 4 key-chunk partials; all 8 waves, 4 rows each (l = out col)
  {
    float* outB = out + (size_t)b * SYN * HH;
#pragma unroll
    for (int i = 0; i < 4; ++i) {
      const int rr = w * 4 + i;        // 0..31 within the 32-row block
      const int mrg = rr >> 4;         // which row-group published it
      const int rowIdx = rr & 15;
      const int q = q0 + rr;
      float res = 0.f;
      if (q < vly) {
        float M = -INFINITY;
#pragma unroll
        for (int cc = 0; cc < 4; ++cc)
          M = fmaxf(M, Ml[(cc << 1) | mrg][rowIdx]);
        if (M > -1e37f) {
          float lsum = 0.f, acc = 0.f;
#pragma unroll
          for (int cc = 0; cc < 4; ++cc) {
            const int ww = (cc << 1) | mrg;
            const float wt = exp2f((Ml[ww][rowIdx] - M) * LOG2E);
            lsum += wt * Ll[ww][rowIdx];
            acc += wt * Ol[ww][rowIdx][l];
          }
          res = (lsum > 0.f) ? acc / lsum : 0.f;
        }
      }
      outB[(size_t)q * HH + l] = res;
    }
  }
}

// ---------------------------------------------------------------------------
extern "C" void kernel_launch(void* const* d_in, const int* in_sizes, int n_in,
                              void* d_out, int out_size, void* d_ws, size_t ws_size,
                              hipStream_t stream) {
  const float* x = (const float*)d_in[0];
  const float* y = (const float*)d_in[1];
  const int* vlx = (const int*)d_in[2];
  const int* vly = (const int*)d_in[3];
  const int* uc = (const int*)d_in[4];
  const float* Wq = (const float*)d_in[5];
  const float* Wk = (const float*)d_in[6];
  const float* Wv = (const float*)d_in[7];
  float* out = (float*)d_out;

  char* ws = (char*)d_ws;
  unsigned short* Qb = (unsigned short*)(ws);                // 2 MB
  unsigned short* Kb = (unsigned short*)(ws + (2u << 20));   // 2 MB
  unsigned short* Vt = (unsigned short*)(ws + (4u << 20));   // 2 MB
  unsigned short* Wt = (unsigned short*)(ws + (6u << 20));   // 384 KB

  prep_wt<<<768, 256, 0, stream>>>(Wq, Wk, Wv, Wt);
  proj_kernel<<<512, 256, 0, stream>>>(x, y, Wt, Qb, Kb, Vt);
  flash_kernel<<<512, 512, 0, stream>>>(Qb, Kb, Vt, vlx, vly, uc, out);
}

// Round 6
// 250.157 us; speedup vs baseline: 1.1411x; 1.0714x over previous
//
#include <hip/hip_runtime.h>
#include <hip/hip_bf16.h>
#include <stdint.h>

// Problem constants
#define BBATCH 4
#define SXN 4096
#define SYN 4096
#define DD 1024
#define HH 64

typedef float f32x4 __attribute__((ext_vector_type(4)));
typedef short bf16x8 __attribute__((ext_vector_type(8)));

static __device__ __forceinline__ unsigned short f2bf(float f) {
  // round-to-nearest-even f32 -> bf16 (inputs finite)
  unsigned int u = __float_as_uint(f);
  u += 0x7fffu + ((u >> 16) & 1u);
  return (unsigned short)(u >> 16);
}
static __device__ __forceinline__ float bf2f(unsigned short b) {
  return __uint_as_float(((unsigned int)b) << 16);
}

static __device__ __forceinline__ bf16x8 cvt8(f32x4 lo, f32x4 hi) {
  bf16x8 v;
  v[0] = (short)f2bf(lo[0]); v[1] = (short)f2bf(lo[1]);
  v[2] = (short)f2bf(lo[2]); v[3] = (short)f2bf(lo[3]);
  v[4] = (short)f2bf(hi[0]); v[5] = (short)f2bf(hi[1]);
  v[6] = (short)f2bf(hi[2]); v[7] = (short)f2bf(hi[3]);
  return v;
}

// async global->LDS DMA, 16B per lane; LDS dest = wave-uniform base + lane*16
static __device__ __forceinline__ void gload_lds16(const void* g, void* l) {
  __builtin_amdgcn_global_load_lds(
      (const __attribute__((address_space(1))) unsigned int*)g,
      (__attribute__((address_space(3))) unsigned int*)l, 16, 0, 0);
}

// ---------------------------------------------------------------------------
// Kernel 0: W [1024][64] f32 -> Wt [3][64][1024] bf16 (0=Wk, 1=Wv, 2=Wq)
// ---------------------------------------------------------------------------
__global__ __launch_bounds__(256) void prep_wt(
    const float* __restrict__ Wq, const float* __restrict__ Wk,
    const float* __restrict__ Wv, unsigned short* __restrict__ Wt) {
  int gid = blockIdx.x * 256 + threadIdx.x;  // grid 768 = 3*64*1024/256
  int mat = gid >> 16;
  int k = gid & 1023;
  int h = (gid >> 10) & 63;
  const float* W = (mat == 0) ? Wk : (mat == 1) ? Wv : Wq;
  Wt[gid] = f2bf(W[k * HH + h]);
}

// ---------------------------------------------------------------------------
// Kernel 1: projections (streaming, global_load_lds double-buffered).
//  blocks 0..255   : x rows -> Kb [b][sx][64] and Vt [b][64][sx]
//  blocks 256..511 : y rows -> Qb [b][sy][64] (scale 0.125 folded in)
// LDS x-tile [64][64] f32 linear (DMA requires it); source cols pre-swizzled
// with col16 ^= (row&7); reads apply the same involution (rule #21).
// W-fragment loads batched into register arrays (one waitcnt per 8 loads).
// ---------------------------------------------------------------------------
__global__ __launch_bounds__(256, 4) void proj_kernel(
    const float* __restrict__ xin, const float* __restrict__ yin,
    const unsigned short* __restrict__ Wt,
    unsigned short* __restrict__ Qb, unsigned short* __restrict__ Kb,
    unsigned short* __restrict__ Vt) {
  __shared__ __align__(16) float xa[2][64 * 64];  // 2 x 16 KB
  const int tid = threadIdx.x;
  const int w = tid >> 6, l = tid & 63;
  const int li = l & 15, lg = l >> 4;
  const bool qpath = blockIdx.x >= 256;
  const int row0 = (qpath ? (blockIdx.x - 256) : (int)blockIdx.x) * 64;
  const float* src = qpath ? yin : xin;
  const unsigned short* WtA = qpath ? (Wt + 2 * 65536) : Wt;  // Wq or Wk
  const unsigned short* WtB = Wt + 65536;                     // Wv

  f32x4 acc0[4], acc1[4];
  const f32x4 z4 = {0.f, 0.f, 0.f, 0.f};
#pragma unroll
  for (int i = 0; i < 4; ++i) { acc0[i] = z4; acc1[i] = z4; }

  // stage chunk kc (64 f32 cols) into buffer: per wave 4 DMA issues of 1KB
  auto stage = [&](int bsel, int kc) {
#pragma unroll
    for (int i = 0; i < 4; ++i) {
      const int r = i * 16 + w * 4 + (l >> 4);      // tile row this lane feeds
      const int c16 = (l & 15) ^ (r & 7);           // pre-swizzled 16B chunk
      const float* g = src + (size_t)(row0 + r) * DD + kc * 64 + c16 * 4;
      float* lp = &xa[bsel][i * 1024 + w * 256];    // wave-uniform LDS base
      gload_lds16(g, lp);
    }
  };

  int buf = 0;
  stage(0, 0);
  __syncthreads();
  for (int kc = 0; kc < 16; ++kc) {
    if (kc < 15) stage(buf ^ 1, kc + 1);
    const int rrow = w * 16 + li;
    const int swz = (rrow & 7) * 4;  // element-granule XOR (== 16B-chunk XOR)
#pragma unroll
    for (int ks = 0; ks < 2; ++ks) {
      const int base = rrow * 64 + ks * 32 + lg * 8;
      const f32x4 lo = *reinterpret_cast<const f32x4*>(&xa[buf][base ^ swz]);
      const f32x4 hi = *reinterpret_cast<const f32x4*>(&xa[buf][(base + 4) ^ swz]);
      const bf16x8 a = cvt8(lo, hi);
      const int gks = kc * 2 + ks;
      // batch all B-fragment loads first (independent 16B L2 reads)
      bf16x8 bA[4], bB[4];
#pragma unroll
      for (int hb = 0; hb < 4; ++hb)
        bA[hb] = *reinterpret_cast<const bf16x8*>(
            &WtA[(hb * 16 + li) * 1024 + gks * 32 + lg * 8]);
      if (!qpath) {
#pragma unroll
        for (int hb = 0; hb < 4; ++hb)
          bB[hb] = *reinterpret_cast<const bf16x8*>(
              &WtB[(hb * 16 + li) * 1024 + gks * 32 + lg * 8]);
      }
#pragma unroll
      for (int hb = 0; hb < 4; ++hb)
        acc0[hb] = __builtin_amdgcn_mfma_f32_16x16x32_bf16(a, bA[hb], acc0[hb], 0, 0, 0);
      if (!qpath) {
#pragma unroll
        for (int hb = 0; hb < 4; ++hb)
          acc1[hb] = __builtin_amdgcn_mfma_f32_16x16x32_bf16(a, bB[hb], acc1[hb], 0, 0, 0);
      }
    }
    __syncthreads();
    buf ^= 1;
  }

  // epilogue: C/D layout row=(l>>4)*4+r, col=l&15 (m89-verified)
  const int rbase = row0 + w * 16 + lg * 4;
  if (qpath) {
#pragma unroll
    for (int hb = 0; hb < 4; ++hb)
#pragma unroll
      for (int r = 0; r < 4; ++r)
        Qb[(size_t)(rbase + r) * HH + hb * 16 + li] = f2bf(acc0[hb][r] * 0.125f);
  } else {
#pragma unroll
    for (int hb = 0; hb < 4; ++hb)
#pragma unroll
      for (int r = 0; r < 4; ++r)
        Kb[(size_t)(rbase + r) * HH + hb * 16 + li] = f2bf(acc0[hb][r]);
    const int b = rbase >> 12;   // row / 4096 (tiles never straddle batches)
    const int sx = rbase & 4095;
#pragma unroll
    for (int hb = 0; hb < 4; ++hb) {
      ushort4 o;
      o.x = f2bf(acc1[hb][0]); o.y = f2bf(acc1[hb][1]);
      o.z = f2bf(acc1[hb][2]); o.w = f2bf(acc1[hb][3]);
      *reinterpret_cast<ushort4*>(
          &Vt[((size_t)b * HH + hb * 16 + li) * SXN + sx]) = o;
    }
  }
}

// ---------------------------------------------------------------------------
// Kernel 2: flash attention, 8-way in-block key-split.
// grid 1024 x 512thr. Block = (batch b, row-group g of 16 q-rows).
// 8 waves = 8 key-chunks of the causal key range (longest wave <= 8 steps).
// Per step: batch-load 8 K-frags (1 waitcnt) -> QK^T MFMA -> issue 8 V-frag
// loads (latency hidden under softmax) -> online softmax -> PV MFMA.
// Partials (m,l,o) merged across the 8 chunks in LDS. Pl/Ol share LDS (union;
// Ol writes only after barrier 1, when all waves are done with Pl).
// Block swizzle: batch pinned to XCDs {2b,2b+1}; longest row-groups first.
// ---------------------------------------------------------------------------
union FlashSm {
  unsigned short Pl[8][16][72];  // 36,864 B (per-wave P relayout)
  float Ol[8][16][64];           // 32,768 B (per-wave output partials)
};

__global__ __launch_bounds__(512, 4) void flash_kernel(
    const unsigned short* __restrict__ Qb, const unsigned short* __restrict__ Kb,
    const unsigned short* __restrict__ Vt, const int* __restrict__ vlx_p,
    const int* __restrict__ vly_p, const int* __restrict__ uc_p,
    float* __restrict__ out) {
  __shared__ __align__(16) FlashSm sm;       // 36 KB
  __shared__ float Ml[8][16], Ll[8][16];     // 1 KB

  const int tid = threadIdx.x;
  const int w = tid >> 6, l = tid & 63;      // w = key-chunk 0..7
  const int li = l & 15, lg = l >> 4;

  const int kblk = blockIdx.x;
  const int b = (kblk & 7) >> 1;                            // XCD-affine batch
  const int g = 255 - (((kblk >> 3) << 1) | (kblk & 1));    // longest first
  const int q0 = g * 16;
  const int vlx = vlx_p[b], vly = vly_p[b];
  const int causal = uc_p[0];
  const float LOG2E = 1.4426950408889634f;

  float* outB = out + (size_t)b * SYN * HH;

  if (q0 >= vly) {  // whole 16-row block masked -> zeros (block-uniform)
    *reinterpret_cast<float2*>(&outB[(size_t)q0 * HH + tid * 2]) =
        make_float2(0.f, 0.f);
    return;
  }

  int kend = causal ? min(vlx, q0 + 16) : vlx;
  if (kend > SXN) kend = SXN;
  const int nst = (kend + 63) >> 6;          // 1..64
  const int s0 = (w * nst) >> 3;
  const int s1 = ((w + 1) * nst) >> 3;

  const unsigned short* KbB = Kb + (size_t)b * SXN * HH;
  const unsigned short* VtB = Vt + (size_t)b * HH * SXN;

  f32x4 o[4];
  float mrun[4], lrun[4];
  const f32x4 z4 = {0.f, 0.f, 0.f, 0.f};
#pragma unroll
  for (int i = 0; i < 4; ++i) { o[i] = z4; mrun[i] = -INFINITY; lrun[i] = 0.f; }

  const int qg0 = q0 + lg * 4;

  if (s1 > s0) {
    const unsigned short* Qrow = Qb + ((size_t)b * SYN + q0 + li) * HH;
    const bf16x8 qa0 = *reinterpret_cast<const bf16x8*>(&Qrow[lg * 8]);
    const bf16x8 qa1 = *reinterpret_cast<const bf16x8*>(&Qrow[32 + lg * 8]);

    for (int s = s0; s < s1; ++s) {
      const int key0 = s << 6;
      // ---- batch all 8 K-fragment loads (independent; single waitcnt) ----
      bf16x8 f[8];
#pragma unroll
      for (int kb = 0; kb < 4; ++kb) {
        const unsigned short* Kr = &KbB[(size_t)(key0 + kb * 16 + li) * HH];
        f[kb * 2] = *reinterpret_cast<const bf16x8*>(&Kr[lg * 8]);
        f[kb * 2 + 1] = *reinterpret_cast<const bf16x8*>(&Kr[32 + lg * 8]);
      }
      f32x4 sa[4];
#pragma unroll
      for (int kb = 0; kb < 4; ++kb) {
        f32x4 acc = z4;
        acc = __builtin_amdgcn_mfma_f32_16x16x32_bf16(qa0, f[kb * 2], acc, 0, 0, 0);
        acc = __builtin_amdgcn_mfma_f32_16x16x32_bf16(qa1, f[kb * 2 + 1], acc, 0, 0, 0);
        sa[kb] = acc;
      }
      // ---- issue V loads now; softmax below hides their latency ----
#pragma unroll
      for (int kh = 0; kh < 2; ++kh)
#pragma unroll
        for (int df = 0; df < 4; ++df)
          f[kh * 4 + df] = *reinterpret_cast<const bf16x8*>(
              &VtB[(size_t)(df * 16 + li) * SXN + key0 + kh * 32 + lg * 8]);

      // ---- mask + online softmax per accumulator row r (q = qg0 + r) ----
#pragma unroll
      for (int r = 0; r < 4; ++r) {
        const int qcap = causal ? (qg0 + r) : 0x7fffffff;
        float sv[4];
#pragma unroll
        for (int kb = 0; kb < 4; ++kb) {
          const int kg = key0 + kb * 16 + li;
          const bool valid = (kg < vlx) && (kg <= qcap);
          sv[kb] = valid ? sa[kb][r] : -1e30f;
        }
        float tm = fmaxf(fmaxf(sv[0], sv[1]), fmaxf(sv[2], sv[3]));
        tm = fmaxf(tm, __shfl_xor(tm, 1));
        tm = fmaxf(tm, __shfl_xor(tm, 2));
        tm = fmaxf(tm, __shfl_xor(tm, 4));
        tm = fmaxf(tm, __shfl_xor(tm, 8));
        const float mn = fmaxf(mrun[r], tm);
        const float corr = exp2f((mrun[r] - mn) * LOG2E);
        mrun[r] = mn;
        float ps = 0.f;
#pragma unroll
        for (int kb = 0; kb < 4; ++kb) {
          const float p = exp2f((sv[kb] - mn) * LOG2E);
          const unsigned short pb = f2bf(p);
          sm.Pl[w][lg * 4 + r][kb * 16 + li] = pb;
          ps += bf2f(pb);  // sum rounded weights -> consistent normalization
        }
        ps += __shfl_xor(ps, 1);
        ps += __shfl_xor(ps, 2);
        ps += __shfl_xor(ps, 4);
        ps += __shfl_xor(ps, 8);
        lrun[r] = lrun[r] * corr + ps;
#pragma unroll
        for (int df = 0; df < 4; ++df) o[df][r] *= corr;
      }

      // ---- PV: A = P (per-wave LDS relayout), B = prefetched V-frags ----
#pragma unroll
      for (int kh = 0; kh < 2; ++kh) {
        const bf16x8 pa =
            *reinterpret_cast<const bf16x8*>(&sm.Pl[w][li][kh * 32 + lg * 8]);
#pragma unroll
        for (int df = 0; df < 4; ++df)
          o[df] = __builtin_amdgcn_mfma_f32_16x16x32_bf16(pa, f[kh * 4 + df],
                                                          o[df], 0, 0, 0);
      }
    }
  }

  __syncthreads();  // barrier 1: every wave is done with its Pl region

  // publish partials (C layout: lane holds rows lg*4+r, cols df*16+li)
#pragma unroll
  for (int df = 0; df < 4; ++df)
#pragma unroll
    for (int r = 0; r < 4; ++r)
      sm.Ol[w][lg * 4 + r][df * 16 + li] = o[df][r];
  if (li == 0) {
#pragma unroll
    for (int r = 0; r < 4; ++r) {
      Ml[w][lg * 4 + r] = mrun[r];
      Ll[w][lg * 4 + r] = lrun[r];
    }
  }
  __syncthreads();  // barrier 2: partials visible

  // merge the 8 key-chunk partials; wave w -> rows w*2, w*2+1; lane l = col
  {
#pragma unroll
    for (int i = 0; i < 2; ++i) {
      const int rr = w * 2 + i;
      const int q = q0 + rr;
      float res = 0.f;
      if (q < vly) {
        float M = -INFINITY;
#pragma unroll
        for (int cc = 0; cc < 8; ++cc) M = fmaxf(M, Ml[cc][rr]);
        if (M > -1e37f) {
          float lsum = 0.f, acc = 0.f;
#pragma unroll
          for (int cc = 0; cc < 8; ++cc) {
            const float wt = exp2f((Ml[cc][rr] - M) * LOG2E);
            lsum += wt * Ll[cc][rr];
            acc += wt * sm.Ol[cc][rr][l];
          }
          res = (lsum > 0.f) ? acc / lsum : 0.f;
        }
      }
      outB[(size_t)q * HH + l] = res;
    }
  }
}

// ---------------------------------------------------------------------------
extern "C" void kernel_launch(void* const* d_in, const int* in_sizes, int n_in,
                              void* d_out, int out_size, void* d_ws, size_t ws_size,
                              hipStream_t stream) {
  const float* x = (const float*)d_in[0];
  const float* y = (const float*)d_in[1];
  const int* vlx = (const int*)d_in[2];
  const int* vly = (const int*)d_in[3];
  const int* uc = (const int*)d_in[4];
  const float* Wq = (const float*)d_in[5];
  const float* Wk = (const float*)d_in[6];
  const float* Wv = (const float*)d_in[7];
  float* out = (float*)d_out;

  char* ws = (char*)d_ws;
  unsigned short* Qb = (unsigned short*)(ws);                // 2 MB
  unsigned short* Kb = (unsigned short*)(ws + (2u << 20));   // 2 MB
  unsigned short* Vt = (unsigned short*)(ws + (4u << 20));   // 2 MB
  unsigned short* Wt = (unsigned short*)(ws + (6u << 20));   // 384 KB

  prep_wt<<<768, 256, 0, stream>>>(Wq, Wk, Wv, Wt);
  proj_kernel<<<512, 256, 0, stream>>>(x, y, Wt, Qb, Kb, Vt);
  flash_kernel<<<1024, 512, 0, stream>>>(Qb, Kb, Vt, vlx, vly, uc, out);
}

// Round 7
// 248.172 us; speedup vs baseline: 1.1502x; 1.0080x over previous
//
#include <hip/hip_runtime.h>
#include <hip/hip_bf16.h>
#include <stdint.h>

// Problem constants
#define BBATCH 4
#define SXN 4096
#define SYN 4096
#define DD 1024
#define HH 64

typedef float f32x4 __attribute__((ext_vector_type(4)));
typedef short bf16x8 __attribute__((ext_vector_type(8)));

static __device__ __forceinline__ unsigned short f2bf(float f) {
  // round-to-nearest-even f32 -> bf16 (inputs finite)
  unsigned int u = __float_as_uint(f);
  u += 0x7fffu + ((u >> 16) & 1u);
  return (unsigned short)(u >> 16);
}
static __device__ __forceinline__ float bf2f(unsigned short b) {
  return __uint_as_float(((unsigned int)b) << 16);
}

static __device__ __forceinline__ bf16x8 cvt8(f32x4 lo, f32x4 hi) {
  bf16x8 v;
  v[0] = (short)f2bf(lo[0]); v[1] = (short)f2bf(lo[1]);
  v[2] = (short)f2bf(lo[2]); v[3] = (short)f2bf(lo[3]);
  v[4] = (short)f2bf(hi[0]); v[5] = (short)f2bf(hi[1]);
  v[6] = (short)f2bf(hi[2]); v[7] = (short)f2bf(hi[3]);
  return v;
}

// ---------------------------------------------------------------------------
// Kernel 0: W [1024][64] f32 -> Wt [3][64][1024] bf16 (0=Wk, 1=Wv, 2=Wq)
// ---------------------------------------------------------------------------
__global__ __launch_bounds__(256) void prep_wt(
    const float* __restrict__ Wq, const float* __restrict__ Wk,
    const float* __restrict__ Wv, unsigned short* __restrict__ Wt) {
  int gid = blockIdx.x * 256 + threadIdx.x;  // grid 768 = 3*64*1024/256
  int mat = gid >> 16;
  int k = gid & 1023;
  int h = (gid >> 10) & 63;
  const float* W = (mat == 0) ? Wk : (mat == 1) ? Wv : Wq;
  Wt[gid] = f2bf(W[k * HH + h]);
}

// ---------------------------------------------------------------------------
// Kernel 1: projections — NO LDS, no barriers. Each wave owns 16 output rows.
// A-fragment (8 contiguous bf16 along K) == 32 contiguous bytes of the f32
// source row -> load 2x f32x4 per lane straight from global, cvt in regs.
// Double-buffered register prefetch (aldA/aldB, static indexing per rule #20)
// keeps ~4KB/wave in flight with zero barrier coupling -> HBM-BW-bound.
// waves 0..1023: x rows -> Kb [b][sx][64] + Vt [b][64][sx] (A shared by K,V)
// waves 1024..2047: y rows -> Qb [b][sy][64] (scale 0.125 folded in)
// W-fragments: same addresses across all waves -> L1/L2-hit, batched loads.
// ---------------------------------------------------------------------------
__global__ __launch_bounds__(256, 2) void proj_kernel(
    const float* __restrict__ xin, const float* __restrict__ yin,
    const unsigned short* __restrict__ Wt,
    unsigned short* __restrict__ Qb, unsigned short* __restrict__ Kb,
    unsigned short* __restrict__ Vt) {
  const int tid = threadIdx.x;
  const int w = tid >> 6, l = tid & 63;
  const int li = l & 15, lg = l >> 4;
  const int gwave = blockIdx.x * 4 + w;          // 0..2047
  const bool qpath = gwave >= 1024;
  const int row0 = (gwave & 1023) * 16;          // 16 rows per wave
  const float* src = qpath ? yin : xin;
  const unsigned short* WtA = qpath ? (Wt + 2 * 65536) : Wt;  // Wq or Wk
  const unsigned short* WtB = Wt + 65536;                     // Wv

  // per-lane A source: row (row0+li), starting at col lg*8 (32B per ks-step)
  const float* arow = src + (size_t)(row0 + li) * DD + lg * 8;

  f32x4 acc0[4], acc1[4];
  const f32x4 z4 = {0.f, 0.f, 0.f, 0.f};
#pragma unroll
  for (int i = 0; i < 4; ++i) { acc0[i] = z4; acc1[i] = z4; }

  f32x4 aldA[4], aldB[4];  // named double buffers (static indexing only)

  // prologue: load kc=0 (cols 0..63: ks0 @ +0, ks1 @ +32 floats)
#pragma unroll
  for (int ks = 0; ks < 2; ++ks) {
    aldA[ks * 2]     = *reinterpret_cast<const f32x4*>(arow + ks * 32);
    aldA[ks * 2 + 1] = *reinterpret_cast<const f32x4*>(arow + ks * 32 + 4);
  }

#pragma unroll 1
  for (int kc2 = 0; kc2 < 8; ++kc2) {
    const int kc = kc2 * 2;
    // ---- even iteration: prefetch kc+1 into aldB, compute kc from aldA ----
    {
      const float* nrow = arow + (size_t)(kc + 1) * 64;
#pragma unroll
      for (int ks = 0; ks < 2; ++ks) {
        aldB[ks * 2]     = *reinterpret_cast<const f32x4*>(nrow + ks * 32);
        aldB[ks * 2 + 1] = *reinterpret_cast<const f32x4*>(nrow + ks * 32 + 4);
      }
    }
#pragma unroll
    for (int ks = 0; ks < 2; ++ks) {
      const int gks = kc * 2 + ks;
      bf16x8 bA[4], bB[4];
#pragma unroll
      for (int hb = 0; hb < 4; ++hb)
        bA[hb] = *reinterpret_cast<const bf16x8*>(
            &WtA[(hb * 16 + li) * 1024 + gks * 32 + lg * 8]);
      if (!qpath) {
#pragma unroll
        for (int hb = 0; hb < 4; ++hb)
          bB[hb] = *reinterpret_cast<const bf16x8*>(
              &WtB[(hb * 16 + li) * 1024 + gks * 32 + lg * 8]);
      }
      const bf16x8 a = cvt8(aldA[ks * 2], aldA[ks * 2 + 1]);
#pragma unroll
      for (int hb = 0; hb < 4; ++hb)
        acc0[hb] = __builtin_amdgcn_mfma_f32_16x16x32_bf16(a, bA[hb], acc0[hb], 0, 0, 0);
      if (!qpath) {
#pragma unroll
        for (int hb = 0; hb < 4; ++hb)
          acc1[hb] = __builtin_amdgcn_mfma_f32_16x16x32_bf16(a, bB[hb], acc1[hb], 0, 0, 0);
      }
    }
    // ---- odd iteration: prefetch kc+2 into aldA, compute kc+1 from aldB ----
    if (kc2 < 7) {
      const float* nrow = arow + (size_t)(kc + 2) * 64;
#pragma unroll
      for (int ks = 0; ks < 2; ++ks) {
        aldA[ks * 2]     = *reinterpret_cast<const f32x4*>(nrow + ks * 32);
        aldA[ks * 2 + 1] = *reinterpret_cast<const f32x4*>(nrow + ks * 32 + 4);
      }
    }
#pragma unroll
    for (int ks = 0; ks < 2; ++ks) {
      const int gks = (kc + 1) * 2 + ks;
      bf16x8 bA[4], bB[4];
#pragma unroll
      for (int hb = 0; hb < 4; ++hb)
        bA[hb] = *reinterpret_cast<const bf16x8*>(
            &WtA[(hb * 16 + li) * 1024 + gks * 32 + lg * 8]);
      if (!qpath) {
#pragma unroll
        for (int hb = 0; hb < 4; ++hb)
          bB[hb] = *reinterpret_cast<const bf16x8*>(
              &WtB[(hb * 16 + li) * 1024 + gks * 32 + lg * 8]);
      }
      const bf16x8 a = cvt8(aldB[ks * 2], aldB[ks * 2 + 1]);
#pragma unroll
      for (int hb = 0; hb < 4; ++hb)
        acc0[hb] = __builtin_amdgcn_mfma_f32_16x16x32_bf16(a, bA[hb], acc0[hb], 0, 0, 0);
      if (!qpath) {
#pragma unroll
        for (int hb = 0; hb < 4; ++hb)
          acc1[hb] = __builtin_amdgcn_mfma_f32_16x16x32_bf16(a, bB[hb], acc1[hb], 0, 0, 0);
      }
    }
  }

  // epilogue: C/D layout row=(l>>4)*4+r, col=l&15 (m89-verified)
  const int rbase = row0 + lg * 4;
  if (qpath) {
#pragma unroll
    for (int hb = 0; hb < 4; ++hb)
#pragma unroll
      for (int r = 0; r < 4; ++r)
        Qb[(size_t)(rbase + r) * HH + hb * 16 + li] = f2bf(acc0[hb][r] * 0.125f);
  } else {
#pragma unroll
    for (int hb = 0; hb < 4; ++hb)
#pragma unroll
      for (int r = 0; r < 4; ++r)
        Kb[(size_t)(rbase + r) * HH + hb * 16 + li] = f2bf(acc0[hb][r]);
    const int b = rbase >> 12;   // row / 4096 (16-row tiles never straddle)
    const int sx = rbase & 4095;
#pragma unroll
    for (int hb = 0; hb < 4; ++hb) {
      ushort4 o;
      o.x = f2bf(acc1[hb][0]); o.y = f2bf(acc1[hb][1]);
      o.z = f2bf(acc1[hb][2]); o.w = f2bf(acc1[hb][3]);
      *reinterpret_cast<ushort4*>(
          &Vt[((size_t)b * HH + hb * 16 + li) * SXN + sx]) = o;
    }
  }
}

// ---------------------------------------------------------------------------
// Kernel 2: flash attention, 8-way in-block key-split (unchanged, round 6).
// ---------------------------------------------------------------------------
union FlashSm {
  unsigned short Pl[8][16][72];  // 36,864 B (per-wave P relayout)
  float Ol[8][16][64];           // 32,768 B (per-wave output partials)
};

__global__ __launch_bounds__(512, 4) void flash_kernel(
    const unsigned short* __restrict__ Qb, const unsigned short* __restrict__ Kb,
    const unsigned short* __restrict__ Vt, const int* __restrict__ vlx_p,
    const int* __restrict__ vly_p, const int* __restrict__ uc_p,
    float* __restrict__ out) {
  __shared__ __align__(16) FlashSm sm;       // 36 KB
  __shared__ float Ml[8][16], Ll[8][16];     // 1 KB

  const int tid = threadIdx.x;
  const int w = tid >> 6, l = tid & 63;      // w = key-chunk 0..7
  const int li = l & 15, lg = l >> 4;

  const int kblk = blockIdx.x;
  const int b = (kblk & 7) >> 1;                            // XCD-affine batch
  const int g = 255 - (((kblk >> 3) << 1) | (kblk & 1));    // longest first
  const int q0 = g * 16;
  const int vlx = vlx_p[b], vly = vly_p[b];
  const int causal = uc_p[0];
  const float LOG2E = 1.4426950408889634f;

  float* outB = out + (size_t)b * SYN * HH;

  if (q0 >= vly) {  // whole 16-row block masked -> zeros (block-uniform)
    *reinterpret_cast<float2*>(&outB[(size_t)q0 * HH + tid * 2]) =
        make_float2(0.f, 0.f);
    return;
  }

  int kend = causal ? min(vlx, q0 + 16) : vlx;
  if (kend > SXN) kend = SXN;
  const int nst = (kend + 63) >> 6;          // 1..64
  const int s0 = (w * nst) >> 3;
  const int s1 = ((w + 1) * nst) >> 3;

  const unsigned short* KbB = Kb + (size_t)b * SXN * HH;
  const unsigned short* VtB = Vt + (size_t)b * HH * SXN;

  f32x4 o[4];
  float mrun[4], lrun[4];
  const f32x4 z4 = {0.f, 0.f, 0.f, 0.f};
#pragma unroll
  for (int i = 0; i < 4; ++i) { o[i] = z4; mrun[i] = -INFINITY; lrun[i] = 0.f; }

  const int qg0 = q0 + lg * 4;

  if (s1 > s0) {
    const unsigned short* Qrow = Qb + ((size_t)b * SYN + q0 + li) * HH;
    const bf16x8 qa0 = *reinterpret_cast<const bf16x8*>(&Qrow[lg * 8]);
    const bf16x8 qa1 = *reinterpret_cast<const bf16x8*>(&Qrow[32 + lg * 8]);

    for (int s = s0; s < s1; ++s) {
      const int key0 = s << 6;
      // ---- batch all 8 K-fragment loads (independent; single waitcnt) ----
      bf16x8 f[8];
#pragma unroll
      for (int kb = 0; kb < 4; ++kb) {
        const unsigned short* Kr = &KbB[(size_t)(key0 + kb * 16 + li) * HH];
        f[kb * 2] = *reinterpret_cast<const bf16x8*>(&Kr[lg * 8]);
        f[kb * 2 + 1] = *reinterpret_cast<const bf16x8*>(&Kr[32 + lg * 8]);
      }
      f32x4 sa[4];
#pragma unroll
      for (int kb = 0; kb < 4; ++kb) {
        f32x4 acc = z4;
        acc = __builtin_amdgcn_mfma_f32_16x16x32_bf16(qa0, f[kb * 2], acc, 0, 0, 0);
        acc = __builtin_amdgcn_mfma_f32_16x16x32_bf16(qa1, f[kb * 2 + 1], acc, 0, 0, 0);
        sa[kb] = acc;
      }
      // ---- issue V loads now; softmax below hides their latency ----
#pragma unroll
      for (int kh = 0; kh < 2; ++kh)
#pragma unroll
        for (int df = 0; df < 4; ++df)
          f[kh * 4 + df] = *reinterpret_cast<const bf16x8*>(
              &VtB[(size_t)(df * 16 + li) * SXN + key0 + kh * 32 + lg * 8]);

      // ---- mask + online softmax per accumulator row r (q = qg0 + r) ----
#pragma unroll
      for (int r = 0; r < 4; ++r) {
        const int qcap = causal ? (qg0 + r) : 0x7fffffff;
        float sv[4];
#pragma unroll
        for (int kb = 0; kb < 4; ++kb) {
          const int kg = key0 + kb * 16 + li;
          const bool valid = (kg < vlx) && (kg <= qcap);
          sv[kb] = valid ? sa[kb][r] : -1e30f;
        }
        float tm = fmaxf(fmaxf(sv[0], sv[1]), fmaxf(sv[2], sv[3]));
        tm = fmaxf(tm, __shfl_xor(tm, 1));
        tm = fmaxf(tm, __shfl_xor(tm, 2));
        tm = fmaxf(tm, __shfl_xor(tm, 4));
        tm = fmaxf(tm, __shfl_xor(tm, 8));
        const float mn = fmaxf(mrun[r], tm);
        const float corr = exp2f((mrun[r] - mn) * LOG2E);
        mrun[r] = mn;
        float ps = 0.f;
#pragma unroll
        for (int kb = 0; kb < 4; ++kb) {
          const float p = exp2f((sv[kb] - mn) * LOG2E);
          const unsigned short pb = f2bf(p);
          sm.Pl[w][lg * 4 + r][kb * 16 + li] = pb;
          ps += bf2f(pb);  // sum rounded weights -> consistent normalization
        }
        ps += __shfl_xor(ps, 1);
        ps += __shfl_xor(ps, 2);
        ps += __shfl_xor(ps, 4);
        ps += __shfl_xor(ps, 8);
        lrun[r] = lrun[r] * corr + ps;
#pragma unroll
        for (int df = 0; df < 4; ++df) o[df][r] *= corr;
      }

      // ---- PV: A = P (per-wave LDS relayout), B = prefetched V-frags ----
#pragma unroll
      for (int kh = 0; kh < 2; ++kh) {
        const bf16x8 pa =
            *reinterpret_cast<const bf16x8*>(&sm.Pl[w][li][kh * 32 + lg * 8]);
#pragma unroll
        for (int df = 0; df < 4; ++df)
          o[df] = __builtin_amdgcn_mfma_f32_16x16x32_bf16(pa, f[kh * 4 + df],
                                                          o[df], 0, 0, 0);
      }
    }
  }

  __syncthreads();  // barrier 1: every wave is done with its Pl region

  // publish partials (C layout: lane holds rows lg*4+r, cols df*16+li)
#pragma unroll
  for (int df = 0; df < 4; ++df)
#pragma unroll
    for (int r = 0; r < 4; ++r)
      sm.Ol[w][lg * 4 + r][df * 16 + li] = o[df][r];
  if (li == 0) {
#pragma unroll
    for (int r = 0; r < 4; ++r) {
      Ml[w][lg * 4 + r] = mrun[r];
      Ll[w][lg * 4 + r] = lrun[r];
    }
  }
  __syncthreads();  // barrier 2: partials visible

  // merge the 8 key-chunk partials; wave w -> rows w*2, w*2+1; lane l = col
  {
#pragma unroll
    for (int i = 0; i < 2; ++i) {
      const int rr = w * 2 + i;
      const int q = q0 + rr;
      float res = 0.f;
      if (q < vly) {
        float M = -INFINITY;
#pragma unroll
        for (int cc = 0; cc < 8; ++cc) M = fmaxf(M, Ml[cc][rr]);
        if (M > -1e37f) {
          float lsum = 0.f, acc = 0.f;
#pragma unroll
          for (int cc = 0; cc < 8; ++cc) {
            const float wt = exp2f((Ml[cc][rr] - M) * LOG2E);
            lsum += wt * Ll[cc][rr];
            acc += wt * sm.Ol[cc][rr][l];
          }
          res = (lsum > 0.f) ? acc / lsum : 0.f;
        }
      }
      outB[(size_t)q * HH + l] = res;
    }
  }
}

// ---------------------------------------------------------------------------
extern "C" void kernel_launch(void* const* d_in, const int* in_sizes, int n_in,
                              void* d_out, int out_size, void* d_ws, size_t ws_size,
                              hipStream_t stream) {
  const float* x = (const float*)d_in[0];
  const float* y = (const float*)d_in[1];
  const int* vlx = (const int*)d_in[2];
  const int* vly = (const int*)d_in[3];
  const int* uc = (const int*)d_in[4];
  const float* Wq = (const float*)d_in[5];
  const float* Wk = (const float*)d_in[6];
  const float* Wv = (const float*)d_in[7];
  float* out = (float*)d_out;

  char* ws = (char*)d_ws;
  unsigned short* Qb = (unsigned short*)(ws);                // 2 MB
  unsigned short* Kb = (unsigned short*)(ws + (2u << 20));   // 2 MB
  unsigned short* Vt = (unsigned short*)(ws + (4u << 20));   // 2 MB
  unsigned short* Wt = (unsigned short*)(ws + (6u << 20));   // 384 KB

  prep_wt<<<768, 256, 0, stream>>>(Wq, Wk, Wv, Wt);
  proj_kernel<<<512, 256, 0, stream>>>(x, y, Wt, Qb, Kb, Vt);
  flash_kernel<<<1024, 512, 0, stream>>>(Qb, Kb, Vt, vlx, vly, uc, out);
}